// Round 5
// baseline (456.993 us; speedup 1.0000x reference)
//
#include <hip/hip_runtime.h>

// PWC-Net cost volume, fp32. B=4, C=128, H=256, W=448, 81 shifts.
// out[b, di*9+dj, h, w] = (1/128) * sum_c feat1[b,c,h,w] * feat2[b,c,h+di-4,w+dj-4]
//
// Barrier-free design: ONE WAVE per (b, h, di) item (9216 waves). No LDS, no
// __syncthreads, no waitcnt asm — pure TLP. Lane owns 8 consecutive w
// (m = lane, 56 active lanes). Per channel: feat1 8 floats (2xb128), feat2
// 16-float window cols 8m-4..8m+11 (4xb128, 16B-aligned) -> 72 FMAs; the
// 9-dj reuse of the window lives in registers. Cross-lane/wave overlap is
// absorbed by L1/L2 (blocks XCD-swizzled so h-neighbors share an L2).
// Edge atoms / out-of-range rows read a zeroed 256B of d_ws with step 0.

__global__ __launch_bounds__(256, 4) void cost_volume_kernel(
    const float* __restrict__ feat1,
    const float* __restrict__ feat2,
    const float* __restrict__ zws,
    float* __restrict__ out)
{
    constexpr int C = 128, H = 256, W = 448;
    constexpr size_t HW = (size_t)H * W;

    const int tid  = threadIdx.x;
    const int wid  = tid >> 6;
    const int lane = tid & 63;

    // 2304 blocks; XCD-contiguous item mapping (2304 = 8*288, bijective).
    const int swz  = (blockIdx.x & 7) * 288 + (blockIdx.x >> 3);
    const int item = swz * 4 + wid;          // 0..9215
    const int di   = item % 9;
    const int bh   = item / 9;               // 0..1023
    const int h    = bh & 255;
    const int b    = bh >> 8;

    const int m   = (lane < 56) ? lane : 55; // 8-px group index
    const int px0 = m << 3;
    const int hr  = h + di - 4;
    const bool rowok = (hr >= 0) && (hr < H);

    // feat1 pointer (always valid: floats px0..px0+7 <= 447).
    const float* f1 = feat1 + ((size_t)b * C * H + (size_t)h) * W + px0;

    // feat2 window: 4 atoms, float offsets px0-4+4k; valid iff 0<=fo<=444.
    const float* f2row = feat2 + ((size_t)b * C * H + (size_t)(rowok ? hr : 0)) * W;
    const float* q0; const float* q1; const float* q2; const float* q3;
    size_t s0, s1, s2, s3;
    {
        const int fo0 = px0 - 4, fo1 = px0, fo2 = px0 + 4, fo3 = px0 + 8;
        const bool ok0 = rowok && (fo0 >= 0);
        const bool ok3 = rowok && (fo3 <= 444);
        q0 = ok0 ? (f2row + fo0) : zws;  s0 = ok0 ? HW : 0;
        q1 = rowok ? (f2row + fo1) : zws; s1 = rowok ? HW : 0;
        q2 = rowok ? (f2row + fo2) : zws; s2 = rowok ? HW : 0;
        q3 = ok3 ? (f2row + fo3) : zws;  s3 = ok3 ? HW : 0;
    }

    float acc[9][8];
#pragma unroll
    for (int j = 0; j < 9; ++j)
#pragma unroll
        for (int p = 0; p < 8; ++p) acc[j][p] = 0.0f;

#pragma unroll 2
    for (int c = 0; c < C; ++c) {
        const float4 a0 = *(const float4*)(f1);
        const float4 a1 = *(const float4*)(f1 + 4);
        const float4 w0 = *(const float4*)(q0);
        const float4 w1 = *(const float4*)(q1);
        const float4 w2 = *(const float4*)(q2);
        const float4 w3 = *(const float4*)(q3);
        f1 += HW; q0 += s0; q1 += s1; q2 += s2; q3 += s3;

        const float a[8]  = {a0.x, a0.y, a0.z, a0.w, a1.x, a1.y, a1.z, a1.w};
        const float w[16] = {w0.x, w0.y, w0.z, w0.w, w1.x, w1.y, w1.z, w1.w,
                             w2.x, w2.y, w2.z, w2.w, w3.x, w3.y, w3.z, w3.w};
#pragma unroll
        for (int dj = 0; dj < 9; ++dj)
#pragma unroll
            for (int p = 0; p < 8; ++p)
                acc[dj][p] = fmaf(a[p], w[dj + p], acc[dj][p]);
    }

    if (lane < 56) {
        const float s = 1.0f / 128.0f;
        float* ob = out + (((size_t)(b * 81 + di * 9)) * H + h) * W + px0;
#pragma unroll
        for (int dj = 0; dj < 9; ++dj) {
            float4 o0, o1;
            o0.x = acc[dj][0] * s; o0.y = acc[dj][1] * s;
            o0.z = acc[dj][2] * s; o0.w = acc[dj][3] * s;
            o1.x = acc[dj][4] * s; o1.y = acc[dj][5] * s;
            o1.z = acc[dj][6] * s; o1.w = acc[dj][7] * s;
            float* op = ob + (size_t)dj * HW;
            *(float4*)(op)     = o0;
            *(float4*)(op + 4) = o1;
        }
    }
}

extern "C" void kernel_launch(void* const* d_in, const int* in_sizes, int n_in,
                              void* d_out, int out_size, void* d_ws, size_t ws_size,
                              hipStream_t stream) {
    const float* feat1 = (const float*)d_in[0];
    const float* feat2 = (const float*)d_in[1];
    float* out = (float*)d_out;
    // Zero source for edge/out-of-range window atoms (each lane reads <=16B).
    hipMemsetAsync(d_ws, 0, 256, stream);
    cost_volume_kernel<<<dim3(2304), dim3(256), 0, stream>>>(
        feat1, feat2, (const float*)d_ws, out);
}